// Round 4
// baseline (24138.365 us; speedup 1.0000x reference)
//
#include <hip/hip_runtime.h>
#include <hip/hip_bf16.h>

// R4 DISCRIMINATOR: R3's line-audited fp32 VALU LSTM core, but store FP32 to d_out.
// R2 (MFMA) and R3 (VALU) gave bit-identical absmax=1.003906 with bf16 stores ->
// the bug is in output interpretation, not compute. This round's single scalar
// (absmax) separates 4 hypotheses:
//   PASS            -> d_out is fp32 (store dtype was the only bug all along)
//   absmax >= 1e3   -> d_out is bf16-read (fp32 bits as bf16 pairs -> wild exponents)
//   absmax 1.003906 -> stale binary on eval side
//   absmax 0.62     -> writes not landing in d_out
//
// Shapes: N=640 seqs (B*Q, flat order = identity), T=100, D=H=512. Gates i,f,g,o.
// Block = 64 seqs x 16 hcols, 256 threads; thread owns (1 hcol x 4 seqs x 4 gates).

#define T_ 100
#define D_ 512
#define H_ 512
#define N_ 640
#define SKP 132  // padded LDS row stride (floats)

__device__ __forceinline__ float sigmoidf_(float x) {
    return 1.0f / (1.0f + __expf(-x));
}

__global__ __launch_bounds__(256) void lstm_step_valu(
    const float* __restrict__ x,      // [N,T,D]
    const float* __restrict__ Wih,    // [4H, D]
    const float* __restrict__ Whh,    // [4H, H]
    const float* __restrict__ bih,    // [4H]
    const float* __restrict__ bhh,    // [4H]
    const float* __restrict__ hprev,  // [N,H] fp32
    float* __restrict__ hnext,        // [N,H] fp32
    float* __restrict__ cbuf,         // [N,H] fp32
    float* __restrict__ out,          // d_out as FP32 on last step, else null
    int t)
{
    __shared__ float S[64 * SKP];

    const int tid = threadIdx.x;
    const int col = tid & 15;   // local hcol
    const int sg  = tid >> 4;   // seq group of 4
    const int s0  = blockIdx.x * 64;
    const int j   = blockIdx.y * 16 + col;

    const int sl = tid >> 2;    // staging: seq-local row
    const int kq = tid & 3;     // staging: k-quarter (32 floats)

    float acc[4][4] = {};       // [seq_i][gate]

    for (int phase = 0; phase < 2; ++phase) {
        const float* Wp = phase ? Whh : Wih;
        const float* Ap = phase ? (hprev + (size_t)(s0 + sl) * H_)
                                : (x + (size_t)(s0 + sl) * (T_ * D_) + (size_t)t * D_);
        for (int kc = 0; kc < 512; kc += 128) {
            __syncthreads();
            #pragma unroll
            for (int u = 0; u < 8; ++u) {
                const int kk = kq * 32 + u * 4;
                *(float4*)&S[sl * SKP + kk] = *(const float4*)(Ap + kc + kk);
            }
            __syncthreads();
            for (int k4 = 0; k4 < 128; k4 += 4) {
                float4 w[4];
                #pragma unroll
                for (int g = 0; g < 4; ++g)
                    w[g] = *(const float4*)(Wp + (size_t)(g * H_ + j) * 512 + kc + k4);
                #pragma unroll
                for (int i = 0; i < 4; ++i) {
                    const float4 sv = *(const float4*)&S[(sg * 4 + i) * SKP + k4];
                    #pragma unroll
                    for (int g = 0; g < 4; ++g) {
                        acc[i][g] += sv.x * w[g].x + sv.y * w[g].y
                                   + sv.z * w[g].z + sv.w * w[g].w;
                    }
                }
            }
        }
    }

    float bsum[4];
    #pragma unroll
    for (int g = 0; g < 4; ++g) bsum[g] = bih[g * H_ + j] + bhh[g * H_ + j];

    #pragma unroll
    for (int i = 0; i < 4; ++i) {
        const int n   = s0 + sg * 4 + i;
        const int idx = n * H_ + j;
        const float gi = sigmoidf_(acc[i][0] + bsum[0]);
        const float gf = sigmoidf_(acc[i][1] + bsum[1]);
        const float gg = tanhf(acc[i][2] + bsum[2]);
        const float go = sigmoidf_(acc[i][3] + bsum[3]);
        const float cn = gf * cbuf[idx] + gi * gg;
        cbuf[idx] = cn;
        const float hv = go * tanhf(cn);
        hnext[idx] = hv;
        if (out) out[idx] = hv;   // FP32 store — the discriminating change
    }
}

extern "C" void kernel_launch(void* const* d_in, const int* in_sizes, int n_in,
                              void* d_out, int out_size, void* d_ws, size_t ws_size,
                              hipStream_t stream) {
    const float* x   = (const float*)d_in[0];
    const float* Wih = (const float*)d_in[1];
    const float* Whh = (const float*)d_in[2];
    const float* bih = (const float*)d_in[3];
    const float* bhh = (const float*)d_in[4];

    // ws: h0 fp32 [N*H], h1 fp32 [N*H], c fp32 [N*H]  (3.93 MB)
    float* h0   = (float*)d_ws;
    float* h1   = h0 + (size_t)N_ * H_;
    float* cbuf = h1 + (size_t)N_ * H_;

    hipMemsetAsync(h0,   0, (size_t)N_ * H_ * sizeof(float), stream);
    hipMemsetAsync(cbuf, 0, (size_t)N_ * H_ * sizeof(float), stream);

    dim3 grid(N_ / 64, H_ / 16);  // 10 x 32 = 320 blocks
    for (int t = 0; t < T_; ++t) {
        const float* hp = (t & 1) ? h1 : h0;
        float* hn       = (t & 1) ? h0 : h1;
        float* o = (t == T_ - 1) ? (float*)d_out : nullptr;
        lstm_step_valu<<<grid, 256, 0, stream>>>(x, Wih, Whh, bih, bhh, hp, hn, cbuf, o, t);
    }
}

// Round 5
// 4174.199 us; speedup vs baseline: 5.7828x; 5.7828x over previous
//
#include <hip/hip_runtime.h>
#include <hip/hip_bf16.h>

// LSTM: N=640 seqs (B*Q fused, flat order verified by R4 PASS), T=100, D=H=512.
// Inputs fp32; OUTPUT d_out is FP32 (confirmed R4). Gates i,f,g,o.
// R5 = R2's MFMA structure (math verified: R2's bf16 stores misread as fp32 exactly
// reproduce the observed 1.0039 absmax; core was correct) + fp32 out store +
// x pre-converted to bf16 in ws (ws_size-gated, fallback = on-the-fly cvt).
//
// Per-step kernel: grid 10x32=320 blocks, 256 thr (4 waves). Block = 64 seqs x
// 16 hcols x 4 gates (wave = gate) -> cell update fused in epilogue.
// MFMA 16x16x32 bf16; A/B fragments are 16B contiguous per lane, loaded from global.

#define T_ 100
#define D_ 512
#define H_ 512
#define N_ 640

using short8  = __attribute__((ext_vector_type(8))) short;  // 8 bf16
using floatx4 = __attribute__((ext_vector_type(4))) float;  // MFMA C/D

__device__ __forceinline__ float sigmoidf_(float x) {
    return 1.0f / (1.0f + __expf(-x));
}

__device__ __forceinline__ unsigned short f2bf(float f) {  // RNE, finite inputs
    union { float f; unsigned int u; } v; v.f = f;
    unsigned int u = v.u;
    u += 0x7fffu + ((u >> 16) & 1u);
    return (unsigned short)(u >> 16);
}

__device__ __forceinline__ short8 ldcvt8(const float* __restrict__ p) {
    const float4 a = *(const float4*)p;
    const float4 b = *(const float4*)(p + 4);
    short8 r;
    r[0] = (short)f2bf(a.x); r[1] = (short)f2bf(a.y);
    r[2] = (short)f2bf(a.z); r[3] = (short)f2bf(a.w);
    r[4] = (short)f2bf(b.x); r[5] = (short)f2bf(b.y);
    r[6] = (short)f2bf(b.z); r[7] = (short)f2bf(b.w);
    return r;
}

// fp32 -> bf16, 8 elements/thread
__global__ __launch_bounds__(256) void cvt_bf16(const float* __restrict__ src,
                                                unsigned short* __restrict__ dst, int n) {
    const int i = (blockIdx.x * 256 + threadIdx.x) * 8;
    if (i < n) {
        const float4 a = *(const float4*)(src + i);
        const float4 b = *(const float4*)(src + i + 4);
        ushort4 o0, o1;
        o0.x = f2bf(a.x); o0.y = f2bf(a.y); o0.z = f2bf(a.z); o0.w = f2bf(a.w);
        o1.x = f2bf(b.x); o1.y = f2bf(b.y); o1.z = f2bf(b.z); o1.w = f2bf(b.w);
        *(ushort4*)(dst + i)     = o0;
        *(ushort4*)(dst + i + 4) = o1;
    }
}

template <bool XBF>
__global__ __launch_bounds__(256) void lstm_step(
    const void* __restrict__ xsrc,             // [N,T,D] bf16 (XBF) or fp32
    const __hip_bfloat16* __restrict__ Wih,    // [4H, D] bf16
    const __hip_bfloat16* __restrict__ Whh,    // [4H, H] bf16
    const float* __restrict__ bih,             // [4H] fp32
    const float* __restrict__ bhh,             // [4H] fp32
    const __hip_bfloat16* __restrict__ hprev,  // [N,H] bf16
    __hip_bfloat16* __restrict__ hnext,        // [N,H] bf16
    float* __restrict__ cbuf,                  // [N,H] fp32
    float* __restrict__ out,                   // d_out fp32 on last step, else null
    int t)
{
    const int tid  = threadIdx.x;
    const int gate = tid >> 6;
    const int lane = tid & 63;
    const int l15  = lane & 15;
    const int quad = lane >> 4;
    const int seq0 = blockIdx.x * 64;
    const int hc0  = blockIdx.y * 16;

    const int r = gate * H_ + hc0 + l15;  // W row = output gate-col for this lane

    floatx4 acc[4] = {};

    // ---- K-part 1: x_t @ W_ih^T ----
    {
        const __hip_bfloat16* wp = Wih + r * D_ + quad * 8;
        if (XBF) {
            const __hip_bfloat16* ap = (const __hip_bfloat16*)xsrc
                + (size_t)(seq0 + l15) * (T_ * D_) + (size_t)t * D_ + quad * 8;
            #pragma unroll 4
            for (int kk = 0; kk < D_; kk += 32) {
                short8 bf = *(const short8*)(wp + kk);
                #pragma unroll
                for (int mi = 0; mi < 4; ++mi) {
                    short8 af = *(const short8*)(ap + (size_t)mi * 16 * (T_ * D_) + kk);
                    acc[mi] = __builtin_amdgcn_mfma_f32_16x16x32_bf16(af, bf, acc[mi], 0, 0, 0);
                }
            }
        } else {
            const float* ap = (const float*)xsrc
                + (size_t)(seq0 + l15) * (T_ * D_) + (size_t)t * D_ + quad * 8;
            #pragma unroll 4
            for (int kk = 0; kk < D_; kk += 32) {
                short8 bf = *(const short8*)(wp + kk);
                #pragma unroll
                for (int mi = 0; mi < 4; ++mi) {
                    short8 af = ldcvt8(ap + (size_t)mi * 16 * (T_ * D_) + kk);
                    acc[mi] = __builtin_amdgcn_mfma_f32_16x16x32_bf16(af, bf, acc[mi], 0, 0, 0);
                }
            }
        }
    }

    // ---- K-part 2: h @ W_hh^T ----
    {
        const __hip_bfloat16* wp = Whh + r * H_ + quad * 8;
        const __hip_bfloat16* ap = hprev + (size_t)(seq0 + l15) * H_ + quad * 8;
        #pragma unroll 4
        for (int kk = 0; kk < H_; kk += 32) {
            short8 bf = *(const short8*)(wp + kk);
            #pragma unroll
            for (int mi = 0; mi < 4; ++mi) {
                short8 af = *(const short8*)(ap + mi * 16 * H_ + kk);
                acc[mi] = __builtin_amdgcn_mfma_f32_16x16x32_bf16(af, bf, acc[mi], 0, 0, 0);
            }
        }
    }

    // ---- exchange gate tiles through LDS; fused cell update ----
    // C/D: col = lane&15 (hcol within 16), row = quad*4 + reg (seq within 16)
    __shared__ float lds[4][64][16];
    #pragma unroll
    for (int mi = 0; mi < 4; ++mi)
        #pragma unroll
        for (int rg = 0; rg < 4; ++rg)
            lds[gate][mi * 16 + quad * 4 + rg][l15] = acc[mi][rg];
    __syncthreads();

    #pragma unroll
    for (int i = 0; i < 4; ++i) {
        const int e   = tid + 256 * i;
        const int sl  = e >> 4;
        const int col = e & 15;
        const int n   = seq0 + sl;
        const int j   = hc0 + col;

        const float bi = bih[0 * H_ + j] + bhh[0 * H_ + j];
        const float bf = bih[1 * H_ + j] + bhh[1 * H_ + j];
        const float bg = bih[2 * H_ + j] + bhh[2 * H_ + j];
        const float bo = bih[3 * H_ + j] + bhh[3 * H_ + j];

        const float gi = sigmoidf_(lds[0][sl][col] + bi);
        const float gf = sigmoidf_(lds[1][sl][col] + bf);
        const float gg = tanhf(lds[2][sl][col] + bg);
        const float go = sigmoidf_(lds[3][sl][col] + bo);

        const int idx = n * H_ + j;
        const float cn = gf * cbuf[idx] + gi * gg;
        cbuf[idx] = cn;
        const float hv = go * tanhf(cn);
        hnext[idx] = __float2bfloat16(hv);
        if (out) out[idx] = hv;   // FP32 store (the R4-confirmed fix)
    }
}

extern "C" void kernel_launch(void* const* d_in, const int* in_sizes, int n_in,
                              void* d_out, int out_size, void* d_ws, size_t ws_size,
                              hipStream_t stream) {
    const float* x    = (const float*)d_in[0];
    const float* Wihf = (const float*)d_in[1];
    const float* Whhf = (const float*)d_in[2];
    const float* bih  = (const float*)d_in[3];
    const float* bhh  = (const float*)d_in[4];

    const size_t nW = (size_t)4 * H_ * D_;       // 1,048,576 per weight matrix
    const size_t nX = (size_t)N_ * T_ * D_;      // 32,768,000
    const size_t nH = (size_t)N_ * H_;           // 327,680

    // ws layout: Wb | Ub | [xb] | h0 | h1 | c
    char* p = (char*)d_ws;
    __hip_bfloat16* Wb = (__hip_bfloat16*)p;             p += nW * 2;
    __hip_bfloat16* Ub = (__hip_bfloat16*)p;             p += nW * 2;
    const size_t need_xb = (size_t)(p - (char*)d_ws) + nX * 2 + nH * 2 * 2 + nH * 4;
    const bool use_xb = ws_size >= need_xb;
    __hip_bfloat16* xb = nullptr;
    if (use_xb) { xb = (__hip_bfloat16*)p;               p += nX * 2; }
    __hip_bfloat16* h0 = (__hip_bfloat16*)p;             p += nH * 2;
    __hip_bfloat16* h1 = (__hip_bfloat16*)p;             p += nH * 2;
    float* cbuf = (float*)p;

    cvt_bf16<<<(int)(nW / (256 * 8)), 256, 0, stream>>>(Wihf, (unsigned short*)Wb, (int)nW);
    cvt_bf16<<<(int)(nW / (256 * 8)), 256, 0, stream>>>(Whhf, (unsigned short*)Ub, (int)nW);
    if (use_xb)
        cvt_bf16<<<(int)(nX / (256 * 8)), 256, 0, stream>>>(x, (unsigned short*)xb, (int)nX);

    hipMemsetAsync(h0,   0, nH * 2, stream);
    hipMemsetAsync(cbuf, 0, nH * 4, stream);

    dim3 grid(N_ / 64, H_ / 16);  // 10 x 32 = 320 blocks
    for (int t = 0; t < T_; ++t) {
        const __hip_bfloat16* hp = (t & 1) ? h1 : h0;
        __hip_bfloat16* hn       = (t & 1) ? h0 : h1;
        float* o = (t == T_ - 1) ? (float*)d_out : nullptr;
        if (use_xb)
            lstm_step<true><<<grid, 256, 0, stream>>>(xb, Wb, Ub, bih, bhh, hp, hn, cbuf, o, t);
        else
            lstm_step<false><<<grid, 256, 0, stream>>>(x, Wb, Ub, bih, bhh, hp, hn, cbuf, o, t);
    }
}

// Round 6
// 1802.740 us; speedup vs baseline: 13.3898x; 2.3155x over previous
//
#include <hip/hip_runtime.h>
#include <hip/hip_bf16.h>

// LSTM: N=640 seqs (B*Q fused), T=100, D=H=512. Inputs fp32; d_out FP32 (R4-verified).
// R6 on top of R5 (passing, 4174 us):
//  1) 1-D grid, hcol-group = bid%32 -> XCD = bid%8 sees only its 4 weight slices
//     (512 KB/XCD, L2-resident across steps; kills ~32 MB/step HBM weight re-fetch).
//  2) A-tile (x_t || h) staged in LDS per 128-K chunk (padded stride 136 elems,
//     2-way-free banks); removes 4x A-load duplication across the block's waves and
//     the L2-latency exposure of 128 global gathers per wave.
// Wave = gate (16 hcols x 4 gates per block, 64 seqs); MFMA 16x16x32 bf16;
// epilogue (verified R2/R5) exchanges gate tiles via LDS, fp32 c, bf16 h ping-pong.

#define T_ 100
#define D_ 512
#define H_ 512
#define N_ 640
#define AS 136  // A-chunk LDS row stride in bf16 elems (128 data + 8 pad)

using short8  = __attribute__((ext_vector_type(8))) short;  // 8 bf16
using floatx4 = __attribute__((ext_vector_type(4))) float;  // MFMA C/D

__device__ __forceinline__ float sigmoidf_(float x) {
    return 1.0f / (1.0f + __expf(-x));
}

__device__ __forceinline__ unsigned short f2bf(float f) {  // RNE, finite inputs
    union { float f; unsigned int u; } v; v.f = f;
    unsigned int u = v.u;
    u += 0x7fffu + ((u >> 16) & 1u);
    return (unsigned short)(u >> 16);
}

__device__ __forceinline__ short8 cvt8(const float* __restrict__ p) {
    const float4 a = *(const float4*)p;
    const float4 b = *(const float4*)(p + 4);
    short8 r;
    r[0] = (short)f2bf(a.x); r[1] = (short)f2bf(a.y);
    r[2] = (short)f2bf(a.z); r[3] = (short)f2bf(a.w);
    r[4] = (short)f2bf(b.x); r[5] = (short)f2bf(b.y);
    r[6] = (short)f2bf(b.z); r[7] = (short)f2bf(b.w);
    return r;
}

// fp32 -> bf16, 8 elements/thread
__global__ __launch_bounds__(256) void cvt_bf16(const float* __restrict__ src,
                                                unsigned short* __restrict__ dst, int n) {
    const int i = (blockIdx.x * 256 + threadIdx.x) * 8;
    if (i < n) {
        const float4 a = *(const float4*)(src + i);
        const float4 b = *(const float4*)(src + i + 4);
        ushort4 o0, o1;
        o0.x = f2bf(a.x); o0.y = f2bf(a.y); o0.z = f2bf(a.z); o0.w = f2bf(a.w);
        o1.x = f2bf(b.x); o1.y = f2bf(b.y); o1.z = f2bf(b.z); o1.w = f2bf(b.w);
        *(ushort4*)(dst + i)     = o0;
        *(ushort4*)(dst + i + 4) = o1;
    }
}

template <bool XBF>
__global__ __launch_bounds__(256) void lstm_step(
    const void* __restrict__ xsrc,             // [N,T,D] bf16 (XBF) else fp32
    const __hip_bfloat16* __restrict__ Wih,    // [4H, D] bf16
    const __hip_bfloat16* __restrict__ Whh,    // [4H, H] bf16
    const float* __restrict__ bih,             // [4H]
    const float* __restrict__ bhh,             // [4H]
    const __hip_bfloat16* __restrict__ hprev,  // [N,H] bf16
    __hip_bfloat16* __restrict__ hnext,        // [N,H] bf16
    float* __restrict__ cbuf,                  // [N,H] fp32
    float* __restrict__ out,                   // d_out fp32 on last step, else null
    int t)
{
    __shared__ __hip_bfloat16 A[64 * AS];  // 17408 B
    __shared__ float G[4][64][16];         // 16384 B

    const int tid  = threadIdx.x;
    const int bid  = blockIdx.x;
    const int grp  = bid & 31;   // hcol-group; bid%8 = XCD -> same-XCD weight slices
    const int sb   = bid >> 5;   // seq-block 0..9
    const int gate = tid >> 6;
    const int lane = tid & 63;
    const int l15  = lane & 15;
    const int quad = lane >> 4;
    const int seq0 = sb * 64;
    const int hc0  = grp * 16;

    const int r = gate * H_ + hc0 + l15;  // W row (output gate-col) for this lane

    floatx4 acc[4] = {};

    #pragma unroll
    for (int phase = 0; phase < 2; ++phase) {
        // A source for staging (row-major [seq][k])
        const __hip_bfloat16* ab = nullptr; const float* af = nullptr; size_t astr;
        if (phase == 0) {
            astr = (size_t)T_ * D_;
            if (XBF) ab = (const __hip_bfloat16*)xsrc + (size_t)seq0 * astr + (size_t)t * D_;
            else     af = (const float*)xsrc          + (size_t)seq0 * astr + (size_t)t * D_;
        } else {
            astr = H_;
            ab = hprev + (size_t)seq0 * H_;
        }
        const __hip_bfloat16* wp = (phase ? Whh : Wih) + (size_t)r * 512 + quad * 8;

        for (int kc = 0; kc < 512; kc += 128) {
            __syncthreads();
            // stage A[64][128] bf16; 1024 x 16B slots, 4 per thread, coalesced by row
            #pragma unroll
            for (int u = 0; u < 4; ++u) {
                const int slot = u * 256 + tid;
                const int row  = slot >> 4;
                const int c16  = slot & 15;
                short8 v;
                if (phase == 0 && !XBF) v = cvt8(af + row * astr + kc + c16 * 8);
                else                    v = *(const short8*)(ab + row * astr + kc + c16 * 8);
                *(short8*)&A[row * AS + c16 * 8] = v;
            }
            __syncthreads();
            #pragma unroll
            for (int ki = 0; ki < 4; ++ki) {   // 4 x K=32 within the chunk
                const short8 bfrag = *(const short8*)(wp + kc + ki * 32);
                #pragma unroll
                for (int mi = 0; mi < 4; ++mi) {
                    const short8 afrag =
                        *(const short8*)&A[(mi * 16 + l15) * AS + ki * 32 + quad * 8];
                    acc[mi] = __builtin_amdgcn_mfma_f32_16x16x32_bf16(afrag, bfrag, acc[mi], 0, 0, 0);
                }
            }
        }
    }

    // ---- epilogue (verified): exchange gate tiles, fused cell update ----
    // C/D: col = lane&15 (hcol), row = quad*4 + reg (seq)
    #pragma unroll
    for (int mi = 0; mi < 4; ++mi)
        #pragma unroll
        for (int rg = 0; rg < 4; ++rg)
            G[gate][mi * 16 + quad * 4 + rg][l15] = acc[mi][rg];
    __syncthreads();

    #pragma unroll
    for (int i = 0; i < 4; ++i) {
        const int e   = tid + 256 * i;
        const int sl  = e >> 4;
        const int col = e & 15;
        const int n   = seq0 + sl;
        const int j   = hc0 + col;

        const float bi = bih[0 * H_ + j] + bhh[0 * H_ + j];
        const float bf = bih[1 * H_ + j] + bhh[1 * H_ + j];
        const float bg = bih[2 * H_ + j] + bhh[2 * H_ + j];
        const float bo = bih[3 * H_ + j] + bhh[3 * H_ + j];

        const float gi = sigmoidf_(G[0][sl][col] + bi);
        const float gf = sigmoidf_(G[1][sl][col] + bf);
        const float gg = tanhf(G[2][sl][col] + bg);
        const float go = sigmoidf_(G[3][sl][col] + bo);

        const int idx = n * H_ + j;
        const float cn = gf * cbuf[idx] + gi * gg;
        cbuf[idx] = cn;
        const float hv = go * tanhf(cn);
        hnext[idx] = __float2bfloat16(hv);
        if (out) out[idx] = hv;
    }
}

extern "C" void kernel_launch(void* const* d_in, const int* in_sizes, int n_in,
                              void* d_out, int out_size, void* d_ws, size_t ws_size,
                              hipStream_t stream) {
    const float* x    = (const float*)d_in[0];
    const float* Wihf = (const float*)d_in[1];
    const float* Whhf = (const float*)d_in[2];
    const float* bih  = (const float*)d_in[3];
    const float* bhh  = (const float*)d_in[4];

    const size_t nW = (size_t)4 * H_ * D_;   // 1,048,576
    const size_t nX = (size_t)N_ * T_ * D_;  // 32,768,000
    const size_t nH = (size_t)N_ * H_;       // 327,680

    // ws: Wb | Ub | [xb] | h0 | h1 | c
    char* p = (char*)d_ws;
    __hip_bfloat16* Wb = (__hip_bfloat16*)p;  p += nW * 2;
    __hip_bfloat16* Ub = (__hip_bfloat16*)p;  p += nW * 2;
    const size_t need_xb = (size_t)(p - (char*)d_ws) + nX * 2 + nH * 2 * 2 + nH * 4;
    const bool use_xb = ws_size >= need_xb;
    __hip_bfloat16* xb = nullptr;
    if (use_xb) { xb = (__hip_bfloat16*)p;    p += nX * 2; }
    __hip_bfloat16* h0 = (__hip_bfloat16*)p;  p += nH * 2;
    __hip_bfloat16* h1 = (__hip_bfloat16*)p;  p += nH * 2;
    float* cbuf = (float*)p;

    cvt_bf16<<<(int)(nW / (256 * 8)), 256, 0, stream>>>(Wihf, (unsigned short*)Wb, (int)nW);
    cvt_bf16<<<(int)(nW / (256 * 8)), 256, 0, stream>>>(Whhf, (unsigned short*)Ub, (int)nW);
    if (use_xb)
        cvt_bf16<<<(int)(nX / (256 * 8)), 256, 0, stream>>>(x, (unsigned short*)xb, (int)nX);

    hipMemsetAsync(h0,   0, nH * 2, stream);
    hipMemsetAsync(cbuf, 0, nH * 4, stream);

    const int nblk = (N_ / 64) * (H_ / 16);  // 320, 1-D (XCD swizzle via bid%32)
    for (int t = 0; t < T_; ++t) {
        const __hip_bfloat16* hp = (t & 1) ? h1 : h0;
        __hip_bfloat16* hn       = (t & 1) ? h0 : h1;
        float* o = (t == T_ - 1) ? (float*)d_out : nullptr;
        if (use_xb)
            lstm_step<true><<<nblk, 256, 0, stream>>>(xb, Wb, Ub, bih, bhh, hp, hn, cbuf, o, t);
        else
            lstm_step<false><<<nblk, 256, 0, stream>>>(x, Wb, Ub, bih, bhh, hp, hn, cbuf, o, t);
    }
}